// Round 1
// baseline (1054.054 us; speedup 1.0000x reference)
//
#include <hip/hip_runtime.h>
#include <math.h>

#define NN 100000

// ---------------- CSR build ----------------

__global__ void hist_kernel(const int* __restrict__ dst, int* __restrict__ cnt, int E) {
    int t = blockIdx.x * blockDim.x + threadIdx.x;
    if (t < E) atomicAdd(&cnt[dst[t]], 1);
}

__global__ void scan1_kernel(const int* __restrict__ cnt, int* __restrict__ ex,
                             int* __restrict__ bsum, int n) {
    __shared__ int sd[1024];
    int t = threadIdx.x;
    int i = blockIdx.x * 1024 + t;
    int v = (i < n) ? cnt[i] : 0;
    sd[t] = v;
    __syncthreads();
    for (int off = 1; off < 1024; off <<= 1) {
        int add = (t >= off) ? sd[t - off] : 0;
        __syncthreads();
        sd[t] += add;
        __syncthreads();
    }
    if (i < n) ex[i] = sd[t] - v;           // exclusive prefix within block
    if (t == 1023) bsum[blockIdx.x] = sd[1023];
}

__global__ void scan2_kernel(int* __restrict__ bsum, int nb) {
    __shared__ int sd[128];
    int t = threadIdx.x;
    int v = (t < nb) ? bsum[t] : 0;
    sd[t] = v;
    __syncthreads();
    for (int off = 1; off < 128; off <<= 1) {
        int add = (t >= off) ? sd[t - off] : 0;
        __syncthreads();
        sd[t] += add;
        __syncthreads();
    }
    if (t < nb) bsum[t] = sd[t] - v;        // exclusive block offsets
}

__global__ void finalize_kernel(const int* __restrict__ cnt, int* __restrict__ row_off,
                                int* __restrict__ cursor, float* __restrict__ dinv,
                                const int* __restrict__ bsum, int n) {
    int i = blockIdx.x * blockDim.x + threadIdx.x;
    if (i < n) {
        int r = row_off[i] + bsum[i >> 10];
        row_off[i] = r;
        cursor[i] = r;
        dinv[i] = rsqrtf((float)cnt[i] + 1.0f);   // +1 self-loop
    }
}

__global__ void scatter_kernel(const int* __restrict__ src, const int* __restrict__ dst,
                               int* __restrict__ cursor, int* __restrict__ nbr, int E) {
    int t = blockIdx.x * blockDim.x + threadIdx.x;
    if (t < E) {
        int d = dst[t];
        int pos = atomicAdd(&cursor[d], 1);
        nbr[pos] = src[t];
    }
}

// ---------------- GEMM: y[r] = (x[r] @ W) * dinv[r] ----------------
// W staged in LDS; lane = output channel; 8 rows per wave; x loads are
// wave-uniform (broadcast) float4 reads.

template <int K, int C>
__global__ __launch_bounds__(512) void gemm_kernel(const float* __restrict__ x,
                                                   const float* __restrict__ W,
                                                   const float* __restrict__ dinv,
                                                   float* __restrict__ y, int n) {
    __shared__ float Wl[K * C];
    for (int i = threadIdx.x; i < (K * C) / 4; i += blockDim.x)
        ((float4*)Wl)[i] = ((const float4*)W)[i];
    __syncthreads();

    const int wave = threadIdx.x >> 6;
    const int lane = threadIdx.x & 63;
    const int cc = (lane < C) ? lane : (C - 1);   // clamp for LDS reads
    const int ngroups = n / 8;                    // 100000/8 = 12500 exact
    const int wpb = blockDim.x >> 6;
    const int gstride = gridDim.x * wpb;

    for (int rg = blockIdx.x * wpb + wave; rg < ngroups; rg += gstride) {
        const int r0 = rg * 8;
        float acc[8];
#pragma unroll
        for (int r = 0; r < 8; r++) acc[r] = 0.0f;

        for (int k = 0; k < K; k += 4) {
            float4 xv[8];
#pragma unroll
            for (int r = 0; r < 8; r++)
                xv[r] = *(const float4*)(x + (size_t)(r0 + r) * K + k);
#pragma unroll
            for (int kk = 0; kk < 4; kk++) {
                float w = Wl[(k + kk) * C + cc];
#pragma unroll
                for (int r = 0; r < 8; r++)
                    acc[r] += ((const float*)&xv[r])[kk] * w;
            }
        }
        if (lane < C) {
#pragma unroll
            for (int r = 0; r < 8; r++)
                y[(size_t)(r0 + r) * C + lane] = acc[r] * dinv[r0 + r];
        }
    }
}

// ---------------- Aggregation, C=64 (+bias, ReLU) ----------------
// One wave per node. 4 neighbor-groups x 16 lanes x float4 = 4 neighbors
// in flight; indices broadcast via shfl from a coalesced chunk load.

__global__ __launch_bounds__(256) void agg64_kernel(const float* __restrict__ y,
                                                    const int* __restrict__ row_off,
                                                    const int* __restrict__ cnt,
                                                    const int* __restrict__ nbr,
                                                    const float* __restrict__ dinv,
                                                    const float* __restrict__ b,
                                                    float* __restrict__ out, int n) {
    int node = blockIdx.x * 4 + (threadIdx.x >> 6);
    if (node >= n) return;
    const int l = threadIdx.x & 63;
    const int g = l >> 4;           // 0..3
    const int ci = (l & 15) << 2;   // 0,4,...,60

    const int start = row_off[node];
    const int deg = cnt[node];

    float4 acc = make_float4(0.f, 0.f, 0.f, 0.f);
    for (int base = 0; base < deg; base += 64) {
        const int m = min(64, deg - base);
        int idx = (l < m) ? nbr[start + base + l] : 0;
        for (int j0 = 0; j0 < m; j0 += 4) {
            int jj = j0 + g;                 // <= 63 always
            int s = __shfl(idx, jj);
            if (jj < m) {
                const float4 v = *(const float4*)(y + (size_t)s * 64 + ci);
                acc.x += v.x; acc.y += v.y; acc.z += v.z; acc.w += v.w;
            }
        }
    }
    // reduce across the 4 groups (lanes l, l^16, l^32, l^48)
#pragma unroll
    for (int off = 16; off < 64; off <<= 1) {
        acc.x += __shfl_xor(acc.x, off);
        acc.y += __shfl_xor(acc.y, off);
        acc.z += __shfl_xor(acc.z, off);
        acc.w += __shfl_xor(acc.w, off);
    }
    if (l < 16) {
        const float4 self = *(const float4*)(y + (size_t)node * 64 + ci);
        const float di = dinv[node];
        const float4 bv = *(const float4*)(b + ci);
        float4 r;
        r.x = fmaxf((acc.x + self.x) * di + bv.x, 0.f);
        r.y = fmaxf((acc.y + self.y) * di + bv.y, 0.f);
        r.z = fmaxf((acc.z + self.z) * di + bv.z, 0.f);
        r.w = fmaxf((acc.w + self.w) * di + bv.w, 0.f);
        *(float4*)(out + (size_t)node * 64 + ci) = r;
    }
}

// ---------------- Aggregation, C=40 (+bias) fused with log_softmax ----------------
// 6 neighbor-groups x 10 lanes x float4 (lanes 60..63 idle).

__global__ __launch_bounds__(256) void agg40_lsm_kernel(const float* __restrict__ y,
                                                        const int* __restrict__ row_off,
                                                        const int* __restrict__ cnt,
                                                        const int* __restrict__ nbr,
                                                        const float* __restrict__ dinv,
                                                        const float* __restrict__ b,
                                                        float* __restrict__ out, int n) {
    int node = blockIdx.x * 4 + (threadIdx.x >> 6);
    if (node >= n) return;
    const int l = threadIdx.x & 63;
    const int g = l / 10;           // 0..6 (6 => idle)
    const int ci = (l % 10) * 4;    // 0,4,...,36
    const bool act = (g < 6);

    const int start = row_off[node];
    const int deg = cnt[node];

    float4 acc = make_float4(0.f, 0.f, 0.f, 0.f);
    for (int base = 0; base < deg; base += 64) {
        const int m = min(64, deg - base);
        int idx = (l < m) ? nbr[start + base + l] : 0;
        for (int j0 = 0; j0 < m; j0 += 6) {
            int jj = j0 + g;
            int s = __shfl(idx, jj < 63 ? jj : 63);
            if (act && jj < m) {
                const float4 v = *(const float4*)(y + (size_t)s * 40 + ci);
                acc.x += v.x; acc.y += v.y; acc.z += v.z; acc.w += v.w;
            }
        }
    }
    // reduce groups 1..5 into group 0 (read original acc of lanes l+10k)
    float4 tot = acc;
#pragma unroll
    for (int k = 1; k < 6; k++) {
        int sl = l + k * 10;
        tot.x += __shfl(acc.x, sl & 63);
        tot.y += __shfl(acc.y, sl & 63);
        tot.z += __shfl(acc.z, sl & 63);
        tot.w += __shfl(acc.w, sl & 63);
    }

    const float di = dinv[node];
    const float4 self = *(const float4*)(y + (size_t)node * 40 + ci);
    const float4 bv = *(const float4*)(b + ci);
    float4 h;
    h.x = (tot.x + self.x) * di + bv.x;
    h.y = (tot.y + self.y) * di + bv.y;
    h.z = (tot.z + self.z) * di + bv.z;
    h.w = (tot.w + self.w) * di + bv.w;

    // log_softmax across the 40 values held by lanes 0..9 (reduce over 16 lanes)
    float mx = (l < 10) ? fmaxf(fmaxf(h.x, h.y), fmaxf(h.z, h.w)) : -INFINITY;
#pragma unroll
    for (int off = 8; off > 0; off >>= 1) mx = fmaxf(mx, __shfl_xor(mx, off, 16));
    float es = (l < 10)
                   ? (expf(h.x - mx) + expf(h.y - mx) + expf(h.z - mx) + expf(h.w - mx))
                   : 0.f;
#pragma unroll
    for (int off = 8; off > 0; off >>= 1) es += __shfl_xor(es, off, 16);
    const float ls = mx + logf(es);

    if (l < 10) {
        float4 o;
        o.x = h.x - ls; o.y = h.y - ls; o.z = h.z - ls; o.w = h.w - ls;
        *(float4*)(out + (size_t)node * 40 + ci) = o;
    }
}

// ---------------- launch ----------------

extern "C" void kernel_launch(void* const* d_in, const int* in_sizes, int n_in,
                              void* d_out, int out_size, void* d_ws, size_t ws_size,
                              hipStream_t stream) {
    const float* x  = (const float*)d_in[0];
    const int* edges = (const int*)d_in[1];
    const float* W1 = (const float*)d_in[2];
    const float* b1 = (const float*)d_in[3];
    const float* W2 = (const float*)d_in[4];
    const float* b2 = (const float*)d_in[5];
    float* out = (float*)d_out;

    const int n = NN;
    const int E = in_sizes[1] / 2;

    char* ws = (char*)d_ws;
    size_t off = 0;
    auto alloc = [&](size_t bytes) -> void* {
        void* p = ws + off;
        off += (bytes + 255) & ~(size_t)255;
        return p;
    };
    int*   cnt     = (int*)alloc((size_t)n * 4);
    int*   row_off = (int*)alloc((size_t)n * 4);
    int*   cursor  = (int*)alloc((size_t)n * 4);
    float* dinv    = (float*)alloc((size_t)n * 4);
    int*   bsum    = (int*)alloc(1024 * 4);
    int*   nbr     = (int*)alloc((size_t)E * 4);
    float* h1      = (float*)alloc((size_t)n * 64 * 4);
    float* y1      = (float*)alloc((size_t)n * 64 * 4);
    float* y2      = y1;   // y1 dead after agg1; reuse for layer-2 xw

    const int* src = edges;
    const int* dst = edges + E;

    hipMemsetAsync(cnt, 0, (size_t)n * 4, stream);
    hist_kernel<<<(E + 255) / 256, 256, 0, stream>>>(dst, cnt, E);
    const int nb = (n + 1023) / 1024;   // 98 (<=128 for scan2)
    scan1_kernel<<<nb, 1024, 0, stream>>>(cnt, row_off, bsum, n);
    scan2_kernel<<<1, 128, 0, stream>>>(bsum, nb);
    finalize_kernel<<<(n + 255) / 256, 256, 0, stream>>>(cnt, row_off, cursor, dinv, bsum, n);
    scatter_kernel<<<(E + 255) / 256, 256, 0, stream>>>(src, dst, cursor, nbr, E);

    // layer 1: y1 = (x @ W1) * dinv ; h1 = relu(agg(y1) * dinv + b1)
    gemm_kernel<256, 64><<<512, 512, 0, stream>>>(x, W1, dinv, y1, n);
    agg64_kernel<<<(n + 3) / 4, 256, 0, stream>>>(y1, row_off, cnt, nbr, dinv, b1, h1, n);

    // layer 2: y2 = (h1 @ W2) * dinv ; out = log_softmax(agg(y2) * dinv + b2)
    gemm_kernel<64, 40><<<512, 512, 0, stream>>>(h1, W2, dinv, y2, n);
    agg40_lsm_kernel<<<(n + 3) / 4, 256, 0, stream>>>(y2, row_off, cnt, nbr, dinv, b2, out, n);
}

// Round 2
// 794.428 us; speedup vs baseline: 1.3268x; 1.3268x over previous
//
#include <hip/hip_runtime.h>
#include <math.h>

#define NN 100000

// ---------------- CSR build ----------------

__global__ void hist_kernel(const int* __restrict__ dst, int* __restrict__ cnt, int E) {
    int t = blockIdx.x * blockDim.x + threadIdx.x;
    if (t < E) atomicAdd(&cnt[dst[t]], 1);
}

__global__ void scan1_kernel(const int* __restrict__ cnt, int* __restrict__ ex,
                             int* __restrict__ bsum, int n) {
    __shared__ int sd[1024];
    int t = threadIdx.x;
    int i = blockIdx.x * 1024 + t;
    int v = (i < n) ? cnt[i] : 0;
    sd[t] = v;
    __syncthreads();
    for (int off = 1; off < 1024; off <<= 1) {
        int add = (t >= off) ? sd[t - off] : 0;
        __syncthreads();
        sd[t] += add;
        __syncthreads();
    }
    if (i < n) ex[i] = sd[t] - v;           // exclusive prefix within block
    if (t == 1023) bsum[blockIdx.x] = sd[1023];
}

__global__ void scan2_kernel(int* __restrict__ bsum, int nb) {
    __shared__ int sd[128];
    int t = threadIdx.x;
    int v = (t < nb) ? bsum[t] : 0;
    sd[t] = v;
    __syncthreads();
    for (int off = 1; off < 128; off <<= 1) {
        int add = (t >= off) ? sd[t - off] : 0;
        __syncthreads();
        sd[t] += add;
        __syncthreads();
    }
    if (t < nb) bsum[t] = sd[t] - v;        // exclusive block offsets
}

__global__ void finalize_kernel(const int* __restrict__ cnt, int* __restrict__ row_off,
                                int* __restrict__ cursor, float* __restrict__ dinv,
                                const int* __restrict__ bsum, int n) {
    int i = blockIdx.x * blockDim.x + threadIdx.x;
    if (i < n) {
        int r = row_off[i] + bsum[i >> 10];
        row_off[i] = r;
        cursor[i] = r;
        dinv[i] = rsqrtf((float)cnt[i] + 1.0f);   // +1 self-loop
    }
}

// 8-pass range-filtered counting-sort scatter: pass p only writes dst in
// [p*range,(p+1)*range) so nbr writes cluster in a ~1.6MB window (full-line
// L2 writebacks instead of 3.2M scattered partial lines). Edge list is
// L3-resident after pass 1.
__global__ __launch_bounds__(256) void scatter_kernel(const int* __restrict__ src,
                                                      const int* __restrict__ dst,
                                                      int* __restrict__ cursor,
                                                      int* __restrict__ nbr, int E,
                                                      int range) {
    const int stride = gridDim.x * blockDim.x;
    const int t0 = blockIdx.x * blockDim.x + threadIdx.x;
    for (int p = 0; p < 8; p++) {
        const int lo = p * range;
        const int hi = lo + range;
        for (int t = t0; t < E; t += stride) {
            int d = dst[t];
            if (d >= lo && d < hi) {
                int pos = atomicAdd(&cursor[d], 1);
                nbr[pos] = src[t];
            }
        }
    }
}

// ---------------- GEMM: y[r] = (x[r] @ W) * dinv[r] ----------------
// lane = row (64 rows per wave), all C channels accumulated in registers.
// x reads are per-lane (64B line reused across 16 consecutive k -> L1-hit);
// W reads are wave-uniform (loop-counter indexed) -> scalarized to s_load,
// issued on the scalar pipe in parallel with the FMA stream. No LDS.

template <int K, int C>
__global__ __launch_bounds__(256, 3) void gemm_kernel(const float* __restrict__ x,
                                                      const float* __restrict__ W,
                                                      const float* __restrict__ dinv,
                                                      float* __restrict__ y, int n) {
    constexpr int C4 = C / 4;
    const int lane = threadIdx.x & 63;
    const int wave = (blockIdx.x * blockDim.x + threadIdx.x) >> 6;
    const int nwaves = (gridDim.x * blockDim.x) >> 6;
    const int ntiles = (n + 63) >> 6;

    for (int tile = wave; tile < ntiles; tile += nwaves) {
        const int r = tile * 64 + lane;
        const int rr = (r < n) ? r : (n - 1);        // clamp reads on tail
        const float* __restrict__ xr = x + (size_t)rr * K;

        float4 acc[C4];
#pragma unroll
        for (int i = 0; i < C4; i++) acc[i] = make_float4(0.f, 0.f, 0.f, 0.f);

        for (int k = 0; k < K; k += 4) {
            const float4 xk = *(const float4*)(xr + k);
            const float* __restrict__ w0 = W + (size_t)k * C;
#pragma unroll
            for (int kk = 0; kk < 4; kk++) {
                const float xv = (kk == 0) ? xk.x : (kk == 1) ? xk.y : (kk == 2) ? xk.z : xk.w;
                const float4* __restrict__ wr = (const float4*)(w0 + kk * C);
#pragma unroll
                for (int i = 0; i < C4; i++) {
                    const float4 w = wr[i];
                    acc[i].x = fmaf(xv, w.x, acc[i].x);
                    acc[i].y = fmaf(xv, w.y, acc[i].y);
                    acc[i].z = fmaf(xv, w.z, acc[i].z);
                    acc[i].w = fmaf(xv, w.w, acc[i].w);
                }
            }
        }
        if (r < n) {
            const float di = dinv[r];
            float4* __restrict__ yr = (float4*)(y + (size_t)r * C);
#pragma unroll
            for (int i = 0; i < C4; i++) {
                float4 v;
                v.x = acc[i].x * di; v.y = acc[i].y * di;
                v.z = acc[i].z * di; v.w = acc[i].w * di;
                yr[i] = v;
            }
        }
    }
}

// ---------------- Aggregation, C=64 (+bias, ReLU) ----------------
// One wave per node. 4 neighbor-groups x 16 lanes x float4 = 4 neighbors
// in flight; indices broadcast via shfl from a coalesced chunk load.

__global__ __launch_bounds__(256) void agg64_kernel(const float* __restrict__ y,
                                                    const int* __restrict__ row_off,
                                                    const int* __restrict__ cnt,
                                                    const int* __restrict__ nbr,
                                                    const float* __restrict__ dinv,
                                                    const float* __restrict__ b,
                                                    float* __restrict__ out, int n) {
    int node = blockIdx.x * 4 + (threadIdx.x >> 6);
    if (node >= n) return;
    const int l = threadIdx.x & 63;
    const int g = l >> 4;           // 0..3
    const int ci = (l & 15) << 2;   // 0,4,...,60

    const int start = row_off[node];
    const int deg = cnt[node];

    float4 acc = make_float4(0.f, 0.f, 0.f, 0.f);
    for (int base = 0; base < deg; base += 64) {
        const int m = min(64, deg - base);
        int idx = (l < m) ? nbr[start + base + l] : 0;
        for (int j0 = 0; j0 < m; j0 += 4) {
            int jj = j0 + g;                 // <= 63 always
            int s = __shfl(idx, jj);
            if (jj < m) {
                const float4 v = *(const float4*)(y + (size_t)s * 64 + ci);
                acc.x += v.x; acc.y += v.y; acc.z += v.z; acc.w += v.w;
            }
        }
    }
    // reduce across the 4 groups (lanes l, l^16, l^32, l^48)
#pragma unroll
    for (int off = 16; off < 64; off <<= 1) {
        acc.x += __shfl_xor(acc.x, off);
        acc.y += __shfl_xor(acc.y, off);
        acc.z += __shfl_xor(acc.z, off);
        acc.w += __shfl_xor(acc.w, off);
    }
    if (l < 16) {
        const float4 self = *(const float4*)(y + (size_t)node * 64 + ci);
        const float di = dinv[node];
        const float4 bv = *(const float4*)(b + ci);
        float4 r;
        r.x = fmaxf((acc.x + self.x) * di + bv.x, 0.f);
        r.y = fmaxf((acc.y + self.y) * di + bv.y, 0.f);
        r.z = fmaxf((acc.z + self.z) * di + bv.z, 0.f);
        r.w = fmaxf((acc.w + self.w) * di + bv.w, 0.f);
        *(float4*)(out + (size_t)node * 64 + ci) = r;
    }
}

// ---------------- Aggregation, C=40 (+bias) fused with log_softmax ----------------
// 6 neighbor-groups x 10 lanes x float4 (lanes 60..63 idle).

__global__ __launch_bounds__(256) void agg40_lsm_kernel(const float* __restrict__ y,
                                                        const int* __restrict__ row_off,
                                                        const int* __restrict__ cnt,
                                                        const int* __restrict__ nbr,
                                                        const float* __restrict__ dinv,
                                                        const float* __restrict__ b,
                                                        float* __restrict__ out, int n) {
    int node = blockIdx.x * 4 + (threadIdx.x >> 6);
    if (node >= n) return;
    const int l = threadIdx.x & 63;
    const int g = l / 10;           // 0..6 (6 => idle)
    const int ci = (l % 10) * 4;    // 0,4,...,36
    const bool act = (g < 6);

    const int start = row_off[node];
    const int deg = cnt[node];

    float4 acc = make_float4(0.f, 0.f, 0.f, 0.f);
    for (int base = 0; base < deg; base += 64) {
        const int m = min(64, deg - base);
        int idx = (l < m) ? nbr[start + base + l] : 0;
        for (int j0 = 0; j0 < m; j0 += 6) {
            int jj = j0 + g;
            int s = __shfl(idx, jj < 63 ? jj : 63);
            if (act && jj < m) {
                const float4 v = *(const float4*)(y + (size_t)s * 40 + ci);
                acc.x += v.x; acc.y += v.y; acc.z += v.z; acc.w += v.w;
            }
        }
    }
    // reduce groups 1..5 into group 0 (read original acc of lanes l+10k)
    float4 tot = acc;
#pragma unroll
    for (int k = 1; k < 6; k++) {
        int sl = l + k * 10;
        tot.x += __shfl(acc.x, sl & 63);
        tot.y += __shfl(acc.y, sl & 63);
        tot.z += __shfl(acc.z, sl & 63);
        tot.w += __shfl(acc.w, sl & 63);
    }

    const float di = dinv[node];
    const float4 self = *(const float4*)(y + (size_t)node * 40 + ci);
    const float4 bv = *(const float4*)(b + ci);
    float4 h;
    h.x = (tot.x + self.x) * di + bv.x;
    h.y = (tot.y + self.y) * di + bv.y;
    h.z = (tot.z + self.z) * di + bv.z;
    h.w = (tot.w + self.w) * di + bv.w;

    // log_softmax across the 40 values held by lanes 0..9 (reduce over 16 lanes)
    float mx = (l < 10) ? fmaxf(fmaxf(h.x, h.y), fmaxf(h.z, h.w)) : -INFINITY;
#pragma unroll
    for (int off = 8; off > 0; off >>= 1) mx = fmaxf(mx, __shfl_xor(mx, off, 16));
    float es = (l < 10)
                   ? (expf(h.x - mx) + expf(h.y - mx) + expf(h.z - mx) + expf(h.w - mx))
                   : 0.f;
#pragma unroll
    for (int off = 8; off > 0; off >>= 1) es += __shfl_xor(es, off, 16);
    const float ls = mx + logf(es);

    if (l < 10) {
        float4 o;
        o.x = h.x - ls; o.y = h.y - ls; o.z = h.z - ls; o.w = h.w - ls;
        *(float4*)(out + (size_t)node * 40 + ci) = o;
    }
}

// ---------------- launch ----------------

extern "C" void kernel_launch(void* const* d_in, const int* in_sizes, int n_in,
                              void* d_out, int out_size, void* d_ws, size_t ws_size,
                              hipStream_t stream) {
    const float* x  = (const float*)d_in[0];
    const int* edges = (const int*)d_in[1];
    const float* W1 = (const float*)d_in[2];
    const float* b1 = (const float*)d_in[3];
    const float* W2 = (const float*)d_in[4];
    const float* b2 = (const float*)d_in[5];
    float* out = (float*)d_out;

    const int n = NN;
    const int E = in_sizes[1] / 2;

    char* ws = (char*)d_ws;
    size_t off = 0;
    auto alloc = [&](size_t bytes) -> void* {
        void* p = ws + off;
        off += (bytes + 255) & ~(size_t)255;
        return p;
    };
    int*   cnt     = (int*)alloc((size_t)n * 4);
    int*   row_off = (int*)alloc((size_t)n * 4);
    int*   cursor  = (int*)alloc((size_t)n * 4);
    float* dinv    = (float*)alloc((size_t)n * 4);
    int*   bsum    = (int*)alloc(1024 * 4);
    int*   nbr     = (int*)alloc((size_t)E * 4);
    float* h1      = (float*)alloc((size_t)n * 64 * 4);
    float* y1      = (float*)alloc((size_t)n * 64 * 4);
    float* y2      = y1;   // y1 dead after agg1; reuse for layer-2 xw

    const int* src = edges;
    const int* dst = edges + E;

    hipMemsetAsync(cnt, 0, (size_t)n * 4, stream);
    hist_kernel<<<(E + 255) / 256, 256, 0, stream>>>(dst, cnt, E);
    const int nb = (n + 1023) / 1024;   // 98 (<=128 for scan2)
    scan1_kernel<<<nb, 1024, 0, stream>>>(cnt, row_off, bsum, n);
    scan2_kernel<<<1, 128, 0, stream>>>(bsum, nb);
    finalize_kernel<<<(n + 255) / 256, 256, 0, stream>>>(cnt, row_off, cursor, dinv, bsum, n);
    scatter_kernel<<<1024, 256, 0, stream>>>(src, dst, cursor, nbr, E, (n + 7) / 8);

    // layer 1: y1 = (x @ W1) * dinv ; h1 = relu(agg(y1) * dinv + b1)
    gemm_kernel<256, 64><<<391, 256, 0, stream>>>(x, W1, dinv, y1, n);
    agg64_kernel<<<(n + 3) / 4, 256, 0, stream>>>(y1, row_off, cnt, nbr, dinv, b1, h1, n);

    // layer 2: y2 = (h1 @ W2) * dinv ; out = log_softmax(agg(y2) * dinv + b2)
    gemm_kernel<64, 40><<<391, 256, 0, stream>>>(h1, W2, dinv, y2, n);
    agg40_lsm_kernel<<<(n + 3) / 4, 256, 0, stream>>>(y2, row_off, cnt, nbr, dinv, b2, out, n);
}